// Round 17
// baseline (395.024 us; speedup 1.0000x reference)
//
#include <hip/hip_runtime.h>
#include <math.h>

#define N_ 20000
#define E_ 320000
#define G_ 128
#define IN_ 16
#define H_ 64
#define L_ 4
#define C_ 10
#define AVG_D_LOG 2.8332133440562162f

union F4 { float4 v; float f[4]; };

typedef _Float16 h8 __attribute__((ext_vector_type(8)));
typedef _Float16 h4 __attribute__((ext_vector_type(4)));
typedef float f4x __attribute__((ext_vector_type(4)));
#define MFMA16(a, b, c) __builtin_amdgcn_mfma_f32_16x16x32_f16((a), (b), (c), 0, 0, 0)

// ---------------- fused setup: embed (5000 blk) + weight-prep (1024) + zero (157) ----------------

__global__ __launch_bounds__(256) void k_setup(
    const float* __restrict__ h, const float* __restrict__ embW, const float* __restrict__ embB,
    float* __restrict__ x,
    const float* __restrict__ preW, const float* __restrict__ postW, const float* __restrict__ mixW,
    _Float16* __restrict__ preWT, _Float16* __restrict__ postWT, _Float16* __restrict__ mixWT,
    int* __restrict__ zbase) {
  int bb = blockIdx.x, tid = threadIdx.x;
  if (bb < 5000) {                       // embedding
    int n = bb * 4 + (tid >> 6);
    int c = tid & 63;
    float acc = embB[c];
#pragma unroll
    for (int k = 0; k < IN_; k++) acc += h[n * IN_ + k] * embW[k * H_ + c];
    x[n * H_ + c] = acc;
  } else if (bb < 6024) {                // weight transpose/cast
    int idx = (bb - 5000) * 256 + tid;   // 0 .. 262143
    if (idx < 32768) {                   // preWT [4][128][64]
      int l = idx >> 13, r = idx & 8191;
      int c = r >> 6, k = r & 63;
      preWT[idx] = (_Float16)preW[l * 8192 + k * 64 + c];
    } else if (idx < 245760) {           // postWT [4][64][832]
      int j = idx - 32768;
      int l = j / 53248, r = j % 53248;
      int c = r / 832, k = r % 832;
      postWT[j] = (_Float16)postW[l * 53248 + k * 64 + c];
    } else {                             // mixWT [4][64][64]
      int j = idx - 245760;
      int l = j >> 12, r = j & 4095;
      int c = r >> 6, k = r & 63;
      mixWT[j] = (_Float16)mixW[l * 4096 + k * 64 + c];
    }
  } else {                               // zero deg+cursor
    int i = (bb - 6024) * 256 + tid;
    if (i < 2 * N_) zbase[i] = 0;
  }
}

// ---------------- hist ----------------

__global__ __launch_bounds__(256) void k_hist(const int* __restrict__ dst, int* __restrict__ deg) {
  int e = blockIdx.x * 256 + threadIdx.x;
  if (e < E_) atomicAdd(&deg[dst[e]], 1);
}

// ---------------- scan: offs only ----------------

__global__ __launch_bounds__(1024) void k_scan(const int* __restrict__ deg, int* __restrict__ offs) {
  __shared__ int sh[1024];
  int t = threadIdx.x;
  int base = t * 20;
  int local[20];
  int s = 0;
#pragma unroll
  for (int i = 0; i < 20; i++) {
    int idx = base + i;
    int v = (idx < N_) ? deg[idx] : 0;
    local[i] = s; s += v;
  }
  sh[t] = s;
  __syncthreads();
  for (int off = 1; off < 1024; off <<= 1) {
    int v = (t >= off) ? sh[t - off] : 0;
    __syncthreads();
    sh[t] += v;
    __syncthreads();
  }
  int excl = sh[t] - s;
#pragma unroll
  for (int i = 0; i < 20; i++) {
    int idx = base + i;
    if (idx < N_) offs[idx] = excl + local[i];
  }
  if (t == 0) offs[N_] = sh[1023];
}

// ---------------- fused: scatter (1250) + scalers (79) + pretrans l=0 (625) ----------------

__global__ __launch_bounds__(256) void k_mix(
    const int* __restrict__ src, const int* __restrict__ dst,
    const int* __restrict__ offs, int* __restrict__ cursor, int* __restrict__ csr,
    const int* __restrict__ deg,
    float* __restrict__ ampv, float* __restrict__ attv,
    float* __restrict__ invd, float* __restrict__ hnb,
    const float* __restrict__ x, const _Float16* __restrict__ preWT,
    const float* __restrict__ preB, _Float16* __restrict__ ah, float* __restrict__ b) {
  int bb = blockIdx.x, tid = threadIdx.x;
  if (bb < 1250) {                       // scatter
    int e = bb * 256 + tid;
    if (e < E_) {
      int d = dst[e];
      int pos = offs[d] + atomicAdd(&cursor[d], 1);
      csr[pos] = src[e];
    }
  } else if (bb < 1329) {                // degree scalers
    int idx = (bb - 1250) * 256 + tid;
    if (idx < N_) {
      float d = (float)deg[idx];
      float logd = logf(d + 1.f);
      ampv[idx] = logd / AVG_D_LOG;
      attv[idx] = AVG_D_LOG / fmaxf(logd, 1e-5f);
      invd[idx] = 1.f / fmaxf(d, 1.f);
      hnb[idx] = d > 0.f ? 1.f : 0.f;
    }
  } else {                               // pretrans layer 0 via MFMA
    int n0 = (bb - 1329) * 32;
    int lane = tid & 63, wv = tid >> 6;
    int mt = wv & 1, nh = wv >> 1;
    int l15 = lane & 15, k0q = (lane >> 4) * 8;
    int mrow = n0 + mt * 16 + l15;
    const float* xr = x + (size_t)mrow * 64;
    const _Float16* wb0 = preWT + (size_t)(nh * 64 + l15) * 64 + k0q;
    f4x acc0 = {0.f,0.f,0.f,0.f}, acc1 = {0.f,0.f,0.f,0.f}, acc2 = {0.f,0.f,0.f,0.f}, acc3 = {0.f,0.f,0.f,0.f};
#pragma unroll
    for (int kb = 0; kb < 64; kb += 32) {
      int ko = kb + k0q;
      F4 xa, xb2;
      xa.v = *(const float4*)(xr + ko);
      xb2.v = *(const float4*)(xr + ko + 4);
      h8 af;
      af[0]=(_Float16)xa.f[0]; af[1]=(_Float16)xa.f[1]; af[2]=(_Float16)xa.f[2]; af[3]=(_Float16)xa.f[3];
      af[4]=(_Float16)xb2.f[0]; af[5]=(_Float16)xb2.f[1]; af[6]=(_Float16)xb2.f[2]; af[7]=(_Float16)xb2.f[3];
      acc0 = MFMA16(af, *(const h8*)(wb0 + kb), acc0);
      acc1 = MFMA16(af, *(const h8*)(wb0 + 1024 + kb), acc1);
      acc2 = MFMA16(af, *(const h8*)(wb0 + 2048 + kb), acc2);
      acc3 = MFMA16(af, *(const h8*)(wb0 + 3072 + kb), acc3);
    }
    int rbase = n0 + mt * 16 + (lane >> 4) * 4;
    f4x accs[4] = {acc0, acc1, acc2, acc3};
#pragma unroll
    for (int t = 0; t < 4; t++) {
      int col = nh * 64 + t * 16 + l15;
#pragma unroll
      for (int r = 0; r < 4; r++) {
        int n = rbase + r;
        if (col < 64) ah[(size_t)n * 64 + col] = (_Float16)accs[t][r];
        else          b[(size_t)n * 64 + (col - 64)] = accs[t][r] + preB[col - 64];
      }
    }
  }
}

// ---------------- fused layer (128 threads, 8 nodes, grid 2500) ----------------
// R17: halve block again -> 9.77 independent blocks/CU (R16: 4.88). Phase A
// unchanged per node. Phases B/C run a 16-row MFMA tile with 8 valid rows:
// A-fragment rows 8..15 read garbage LDS, polluting only D rows 8..15 which
// are never stored (stores guarded qr<8, loads clamped).

__global__ __launch_bounds__(128) void k_layer(
    const _Float16* __restrict__ ahin, const float* __restrict__ bin,
    const int* __restrict__ offs, const int* __restrict__ csr,
    const float* __restrict__ invd, const float* __restrict__ hnb,
    const _Float16* __restrict__ WT, const float* __restrict__ Bv,
    const _Float16* __restrict__ mixWT, const float* __restrict__ mixB,
    const float* __restrict__ ampv, const float* __restrict__ attv,
    const float* __restrict__ snorm, float* __restrict__ x,
    const _Float16* __restrict__ preWT, const float* __restrict__ preB,
    _Float16* __restrict__ ahout, float* __restrict__ bout, int do_pre) {
  __shared__ _Float16 aggs[16 * 272];   // rows 8..15 garbage (D rows discarded)
  __shared__ _Float16 ys[16 * 80];
  __shared__ _Float16 xs[16 * 80];
  int tid = threadIdx.x;
  int n0 = blockIdx.x * 8;
  int lane = tid & 63, wv = tid >> 6;   // wv 0..1

  // ---- phase A: thread = (node nl 0..7, quad q 0..15) ----
  {
    int nl = tid >> 4, q = tid & 15;
    int n = n0 + nl;
    int o0 = offs[n];
    int deg = offs[n + 1] - o0;
    float sum[4], sq[4], mx[4], mn[4];
#pragma unroll
    for (int i = 0; i < 4; i++) {
      sum[i] = 0.f; sq[i] = 0.f;
      mx[i] = -__builtin_inff(); mn[i] = __builtin_inff();
    }
    int j = 0;
    for (; j + 3 < deg; j += 4) {
      int s0 = csr[o0 + j];
      int s1 = csr[o0 + j + 1];
      int s2 = csr[o0 + j + 2];
      int s3 = csr[o0 + j + 3];
      h4 a0 = *(const h4*)(ahin + (size_t)s0 * 64 + q * 4);
      h4 a1 = *(const h4*)(ahin + (size_t)s1 * 64 + q * 4);
      h4 a2 = *(const h4*)(ahin + (size_t)s2 * 64 + q * 4);
      h4 a3 = *(const h4*)(ahin + (size_t)s3 * 64 + q * 4);
#pragma unroll
      for (int i = 0; i < 4; i++) {
        float v0 = (float)a0[i], v1 = (float)a1[i], v2 = (float)a2[i], v3 = (float)a3[i];
        sum[i] += (v0 + v1) + (v2 + v3);
        sq[i] += v0 * v0;
        sq[i] += v1 * v1;
        sq[i] += v2 * v2;
        sq[i] += v3 * v3;
        mx[i] = fmaxf(mx[i], fmaxf(fmaxf(v0, v1), fmaxf(v2, v3)));
        mn[i] = fminf(mn[i], fminf(fminf(v0, v1), fminf(v2, v3)));
      }
    }
    for (; j < deg; j++) {
      int s0 = csr[o0 + j];
      h4 a0 = *(const h4*)(ahin + (size_t)s0 * 64 + q * 4);
#pragma unroll
      for (int i = 0; i < 4; i++) {
        float v0 = (float)a0[i];
        sum[i] += v0;
        sq[i] += v0 * v0;
        mx[i] = fmaxf(mx[i], v0);
        mn[i] = fminf(mn[i], v0);
      }
    }
    float inv = invd[n], hn = hnb[n];
    F4 bv; bv.v = *(const float4*)(bin + (size_t)n * 64 + q * 4);
    h4 hm, hx, hmn, hs;
#pragma unroll
    for (int i = 0; i < 4; i++) {
      float mean_a = sum[i] * inv;
      float var = sq[i] * inv - mean_a * mean_a;
      hs[i] = (_Float16)sqrtf(fmaxf(var, 0.f) + 1e-5f);
      bool nb = hn > 0.5f;
      hm[i] = (_Float16)(nb ? (mean_a + bv.f[i]) : 0.f);
      hx[i] = (_Float16)(nb ? (mx[i] + bv.f[i]) : 0.f);
      hmn[i] = (_Float16)(nb ? (mn[i] + bv.f[i]) : 0.f);
    }
    _Float16* ap = aggs + nl * 272 + q * 4;
    *(h4*)(ap) = hm;
    *(h4*)(ap + 64) = hx;
    *(h4*)(ap + 128) = hmn;
    *(h4*)(ap + 192) = hs;
  }
  __syncthreads();

  // ---- phase B: posttrans + mix + graphnorm + residual (2 col-quads/wave) ----
  int l15 = lane & 15, k0q = (lane >> 4) * 8;
  int mrow = n0 + l15; if (mrow > N_ - 1) mrow = N_ - 1;  // rows 8..15 garbage
  const _Float16* ag = aggs + (size_t)l15 * 272 + k0q;
  int col0 = wv * 32 + l15;
  int col1 = col0 + 16;
  const _Float16* w0 = WT + (size_t)col0 * 832 + k0q;
  const _Float16* w1 = WT + (size_t)col1 * 832 + k0q;
  f4x aI0={0.f,0.f,0.f,0.f}, aA0={0.f,0.f,0.f,0.f}, aT0={0.f,0.f,0.f,0.f};
  f4x aI1={0.f,0.f,0.f,0.f}, aA1={0.f,0.f,0.f,0.f}, aT1={0.f,0.f,0.f,0.f};
#pragma unroll 4
  for (int kb = 0; kb < 256; kb += 32) {
    h8 af = *(const h8*)(ag + kb);
    aI0 = MFMA16(af, *(const h8*)(w0 + kb), aI0);
    aI1 = MFMA16(af, *(const h8*)(w1 + kb), aI1);
    aA0 = MFMA16(af, *(const h8*)(w0 + 256 + kb), aA0);
    aA1 = MFMA16(af, *(const h8*)(w1 + 256 + kb), aA1);
    aT0 = MFMA16(af, *(const h8*)(w0 + 512 + kb), aT0);
    aT1 = MFMA16(af, *(const h8*)(w1 + 512 + kb), aT1);
  }
  const float* xr = x + (size_t)mrow * 64;
#pragma unroll
  for (int kb = 0; kb < 64; kb += 32) {
    int ko = kb + k0q;
    F4 xa, xb2;
    xa.v = *(const float4*)(xr + ko);
    xb2.v = *(const float4*)(xr + ko + 4);
    h8 af;
    af[0]=(_Float16)xa.f[0]; af[1]=(_Float16)xa.f[1]; af[2]=(_Float16)xa.f[2]; af[3]=(_Float16)xa.f[3];
    af[4]=(_Float16)xb2.f[0]; af[5]=(_Float16)xb2.f[1]; af[6]=(_Float16)xb2.f[2]; af[7]=(_Float16)xb2.f[3];
    aI0 = MFMA16(af, *(const h8*)(w0 + 768 + kb), aI0);
    aI1 = MFMA16(af, *(const h8*)(w1 + 768 + kb), aI1);
  }
  int qr = (lane >> 4) * 4;
  if (qr < 8) {
    float b0 = Bv[col0], b1 = Bv[col1];
#pragma unroll
    for (int r = 0; r < 4; r++) {
      int n = n0 + qr + r;
      float amp = ampv[n], att = attv[n];
      ys[(qr + r) * 80 + col0] = (_Float16)(aI0[r] + b0 + amp * aA0[r] + att * aT0[r]);
      ys[(qr + r) * 80 + col1] = (_Float16)(aI1[r] + b1 + amp * aA1[r] + att * aT1[r]);
    }
  }
  __syncthreads();
  f4x m0 = {0.f,0.f,0.f,0.f}, m1 = {0.f,0.f,0.f,0.f};
  const _Float16* yr = ys + (size_t)l15 * 80 + k0q;
  const _Float16* mw0 = mixWT + (size_t)col0 * 64 + k0q;
  const _Float16* mw1 = mixWT + (size_t)col1 * 64 + k0q;
#pragma unroll
  for (int kb = 0; kb < 64; kb += 32) {
    h8 af = *(const h8*)(yr + kb);
    m0 = MFMA16(af, *(const h8*)(mw0 + kb), m0);
    m1 = MFMA16(af, *(const h8*)(mw1 + kb), m1);
  }
  if (qr < 8) {
    float mb0 = mixB[col0], mb1 = mixB[col1];
#pragma unroll
    for (int r = 0; r < 4; r++) {
      int n = n0 + qr + r;
      float sn = snorm[n];
      float t0 = m0[r] + mb0; t0 = t0 > 0.f ? t0 : 0.01f * t0;
      float t1 = m1[r] + mb1; t1 = t1 > 0.f ? t1 : 0.01f * t1;
      float* xp = x + (size_t)n * 64;
      float xo0 = xp[col0] + t0 * sn;
      float xo1 = xp[col1] + t1 * sn;
      xp[col0] = xo0;
      xp[col1] = xo1;
      xs[(qr + r) * 80 + col0] = (_Float16)xo0;
      xs[(qr + r) * 80 + col1] = (_Float16)xo1;
    }
  }

  // ---- phase C: pretrans for layer l+1 from LDS x (4 col-chunks/wave) ----
  if (do_pre) {
    __syncthreads();
    const _Float16* xf = xs + (size_t)l15 * 80 + k0q;
    const _Float16* wb0 = preWT + (size_t)(wv * 64 + l15) * 64 + k0q;
    f4x p0 = {0.f,0.f,0.f,0.f}, p1 = {0.f,0.f,0.f,0.f}, p2 = {0.f,0.f,0.f,0.f}, p3 = {0.f,0.f,0.f,0.f};
#pragma unroll
    for (int kb = 0; kb < 64; kb += 32) {
      h8 af = *(const h8*)(xf + kb);
      p0 = MFMA16(af, *(const h8*)(wb0 + kb), p0);
      p1 = MFMA16(af, *(const h8*)(wb0 + 1024 + kb), p1);
      p2 = MFMA16(af, *(const h8*)(wb0 + 2048 + kb), p2);
      p3 = MFMA16(af, *(const h8*)(wb0 + 3072 + kb), p3);
    }
    if (qr < 8) {
      f4x accs[4] = {p0, p1, p2, p3};
#pragma unroll
      for (int t = 0; t < 4; t++) {
        int col = wv * 64 + t * 16 + l15;
#pragma unroll
        for (int r = 0; r < 4; r++) {
          int n = n0 + qr + r;
          if (col < 64) ahout[(size_t)n * 64 + col] = (_Float16)accs[t][r];
          else          bout[(size_t)n * 64 + (col - 64)] = accs[t][r] + preB[col - 64];
        }
      }
    }
  }
}

// ---------------- fused readout: segmented mean (gid sorted) + MLP ----------------

__device__ inline int lower_bound_gid(const int* __restrict__ gid, int val) {
  int lo = 0, hi = N_;
  while (lo < hi) {
    int mid = (lo + hi) >> 1;
    if (gid[mid] < val) lo = mid + 1; else hi = mid;
  }
  return lo;
}

__global__ __launch_bounds__(256) void k_readout_fused(
    const float* __restrict__ x, const int* __restrict__ gid,
    const float* __restrict__ r1W, const float* __restrict__ r1B,
    const float* __restrict__ r2W, const float* __restrict__ r2B,
    const float* __restrict__ r3W, const float* __restrict__ r3B,
    float* __restrict__ out) {
  __shared__ float part[4 * 64];
  __shared__ float hg[64];
  __shared__ float t1[32];
  __shared__ float t2[16];
  int g = blockIdx.x, tid = threadIdx.x;
  int lo = lower_bound_gid(gid, g);
  int hi = lower_bound_gid(gid, g + 1);
  int c = tid & 63, w = tid >> 6;
  float s = 0.f;
  for (int n = lo + w; n < hi; n += 4) s += x[(size_t)n * 64 + c];
  part[w * 64 + c] = s;
  __syncthreads();
  if (w == 0) {
    float tot = part[c] + part[64 + c] + part[128 + c] + part[192 + c];
    float cnt = (float)(hi - lo);
    if (cnt < 1.f) cnt = 1.f;
    hg[c] = tot / cnt;
  }
  __syncthreads();
  if (tid < 32) {
    float acc = r1B[tid];
#pragma unroll 8
    for (int k = 0; k < 64; k++) acc += hg[k] * r1W[k * 32 + tid];
    t1[tid] = fmaxf(acc, 0.f);
  }
  __syncthreads();
  if (tid < 16) {
    float acc = r2B[tid];
#pragma unroll 8
    for (int k = 0; k < 32; k++) acc += t1[k] * r2W[k * 16 + tid];
    t2[tid] = fmaxf(acc, 0.f);
  }
  __syncthreads();
  if (tid < 10) {
    float acc = r3B[tid];
#pragma unroll
    for (int k = 0; k < 16; k++) acc += t2[k] * r3W[k * 10 + tid];
    out[g * 10 + tid] = acc;
  }
}

// ---------------- launch ----------------

extern "C" void kernel_launch(void* const* d_in, const int* in_sizes, int n_in,
                              void* d_out, int out_size, void* d_ws, size_t ws_size,
                              hipStream_t stream) {
  const float* h     = (const float*)d_in[0];
  const float* snorm = (const float*)d_in[1];
  const float* embW  = (const float*)d_in[2];
  const float* embB  = (const float*)d_in[3];
  const float* preW  = (const float*)d_in[4];
  const float* preB  = (const float*)d_in[5];
  const float* postW = (const float*)d_in[6];
  const float* postB = (const float*)d_in[7];
  const float* mixW  = (const float*)d_in[8];
  const float* mixB  = (const float*)d_in[9];
  const float* r1W   = (const float*)d_in[10];
  const float* r1B   = (const float*)d_in[11];
  const float* r2W   = (const float*)d_in[12];
  const float* r2B   = (const float*)d_in[13];
  const float* r3W   = (const float*)d_in[14];
  const float* r3B   = (const float*)d_in[15];
  const int* src     = (const int*)d_in[16];
  const int* dst     = (const int*)d_in[17];
  const int* gid     = (const int*)d_in[18];
  float* out = (float*)d_out;

  char* w = (char*)d_ws;
  float* x        = (float*)w; w += (size_t)N_ * 64 * 4;
  _Float16* ah0   = (_Float16*)w; w += (size_t)N_ * 64 * 2;
  _Float16* ah1   = (_Float16*)w; w += (size_t)N_ * 64 * 2;
  float* b0       = (float*)w; w += (size_t)N_ * 64 * 4;
  float* b1       = (float*)w; w += (size_t)N_ * 64 * 4;
  _Float16* preWT = (_Float16*)w; w += (size_t)4 * 128 * 64 * 2;
  _Float16* postWT= (_Float16*)w; w += (size_t)4 * 64 * 832 * 2;
  _Float16* mixWT = (_Float16*)w; w += (size_t)4 * 64 * 64 * 2;
  float* ampv = (float*)w; w += (size_t)N_ * 4;
  float* attv = (float*)w; w += (size_t)N_ * 4;
  float* invd = (float*)w; w += (size_t)N_ * 4;
  float* hnb  = (float*)w; w += (size_t)N_ * 4;
  int* csr    = (int*)w;   w += (size_t)E_ * 4;
  int* offs   = (int*)w;   w += (size_t)(N_ + 64) * 4;
  int* zbase  = (int*)w;
  int* deg    = (int*)w;   w += (size_t)N_ * 4;
  int* cursor = (int*)w;   w += (size_t)N_ * 4;

  // 1: embed + weight prep + zero deg/cursor
  k_setup<<<6181, 256, 0, stream>>>(h, embW, embB, x, preW, postW, mixW,
                                    preWT, postWT, mixWT, zbase);
  // 2: degree histogram
  k_hist<<<E_ / 256, 256, 0, stream>>>(dst, deg);
  // 3: offs scan
  k_scan<<<1, 1024, 0, stream>>>(deg, offs);
  // 4: scatter + scalers + pretrans(l0)
  k_mix<<<1250 + 79 + 625, 256, 0, stream>>>(src, dst, offs, cursor, csr, deg,
                                             ampv, attv, invd, hnb,
                                             x, preWT, preB, ah0, b0);
  int gb = N_ / 8;  // 2500 blocks
  _Float16* ahs[2] = {ah0, ah1};
  float* bs[2] = {b0, b1};
  for (int l = 0; l < L_; l++) {
    int pin = l & 1, pout = 1 - pin;
    k_layer<<<gb, 128, 0, stream>>>(ahs[pin], bs[pin], offs, csr, invd, hnb,
                                    postWT + (size_t)l * 53248, postB + l * H_,
                                    mixWT + (size_t)l * 4096, mixB + l * H_,
                                    ampv, attv, snorm, x,
                                    preWT + (size_t)(l + 1 < L_ ? l + 1 : 0) * 8192,
                                    preB + (l + 1 < L_ ? l + 1 : 0) * H_,
                                    ahs[pout], bs[pout], l + 1 < L_ ? 1 : 0);
  }
  k_readout_fused<<<G_, 256, 0, stream>>>(x, gid, r1W, r1B, r2W, r2B, r3W, r3B, out);
}

// Round 18
// 327.126 us; speedup vs baseline: 1.2076x; 1.2076x over previous
//
#include <hip/hip_runtime.h>
#include <math.h>

#define N_ 20000
#define E_ 320000
#define G_ 128
#define IN_ 16
#define H_ 64
#define L_ 4
#define C_ 10
#define AVG_D_LOG 2.8332133440562162f

union F4 { float4 v; float f[4]; };

typedef _Float16 h8 __attribute__((ext_vector_type(8)));
typedef _Float16 h4 __attribute__((ext_vector_type(4)));
typedef float f4x __attribute__((ext_vector_type(4)));
#define MFMA16(a, b, c) __builtin_amdgcn_mfma_f32_16x16x32_f16((a), (b), (c), 0, 0, 0)

// ---------------- fused setup: embed (5000 blk) + weight-prep (1024) + zero (157) ----------------

__global__ __launch_bounds__(256) void k_setup(
    const float* __restrict__ h, const float* __restrict__ embW, const float* __restrict__ embB,
    float* __restrict__ x,
    const float* __restrict__ preW, const float* __restrict__ postW, const float* __restrict__ mixW,
    _Float16* __restrict__ preWT, _Float16* __restrict__ postWT, _Float16* __restrict__ mixWT,
    int* __restrict__ zbase) {
  int bb = blockIdx.x, tid = threadIdx.x;
  if (bb < 5000) {                       // embedding
    int n = bb * 4 + (tid >> 6);
    int c = tid & 63;
    float acc = embB[c];
#pragma unroll
    for (int k = 0; k < IN_; k++) acc += h[n * IN_ + k] * embW[k * H_ + c];
    x[n * H_ + c] = acc;
  } else if (bb < 6024) {                // weight transpose/cast
    int idx = (bb - 5000) * 256 + tid;   // 0 .. 262143
    if (idx < 32768) {                   // preWT [4][128][64]
      int l = idx >> 13, r = idx & 8191;
      int c = r >> 6, k = r & 63;
      preWT[idx] = (_Float16)preW[l * 8192 + k * 64 + c];
    } else if (idx < 245760) {           // postWT [4][64][832]
      int j = idx - 32768;
      int l = j / 53248, r = j % 53248;
      int c = r / 832, k = r % 832;
      postWT[j] = (_Float16)postW[l * 53248 + k * 64 + c];
    } else {                             // mixWT [4][64][64]
      int j = idx - 245760;
      int l = j >> 12, r = j & 4095;
      int c = r >> 6, k = r & 63;
      mixWT[j] = (_Float16)mixW[l * 4096 + k * 64 + c];
    }
  } else {                               // zero deg+cursor
    int i = (bb - 6024) * 256 + tid;
    if (i < 2 * N_) zbase[i] = 0;
  }
}

// ---------------- hist ----------------

__global__ __launch_bounds__(256) void k_hist(const int* __restrict__ dst, int* __restrict__ deg) {
  int e = blockIdx.x * 256 + threadIdx.x;
  if (e < E_) atomicAdd(&deg[dst[e]], 1);
}

// ---------------- scan: offs only ----------------

__global__ __launch_bounds__(1024) void k_scan(const int* __restrict__ deg, int* __restrict__ offs) {
  __shared__ int sh[1024];
  int t = threadIdx.x;
  int base = t * 20;
  int local[20];
  int s = 0;
#pragma unroll
  for (int i = 0; i < 20; i++) {
    int idx = base + i;
    int v = (idx < N_) ? deg[idx] : 0;
    local[i] = s; s += v;
  }
  sh[t] = s;
  __syncthreads();
  for (int off = 1; off < 1024; off <<= 1) {
    int v = (t >= off) ? sh[t - off] : 0;
    __syncthreads();
    sh[t] += v;
    __syncthreads();
  }
  int excl = sh[t] - s;
#pragma unroll
  for (int i = 0; i < 20; i++) {
    int idx = base + i;
    if (idx < N_) offs[idx] = excl + local[i];
  }
  if (t == 0) offs[N_] = sh[1023];
}

// ---------------- fused: scatter (1250) + scalers (79) + pretrans l=0 (625) ----------------

__global__ __launch_bounds__(256) void k_mix(
    const int* __restrict__ src, const int* __restrict__ dst,
    const int* __restrict__ offs, int* __restrict__ cursor, int* __restrict__ csr,
    const int* __restrict__ deg,
    float* __restrict__ ampv, float* __restrict__ attv,
    float* __restrict__ invd, float* __restrict__ hnb,
    const float* __restrict__ x, const _Float16* __restrict__ preWT,
    const float* __restrict__ preB, _Float16* __restrict__ ah, float* __restrict__ b) {
  int bb = blockIdx.x, tid = threadIdx.x;
  if (bb < 1250) {                       // scatter
    int e = bb * 256 + tid;
    if (e < E_) {
      int d = dst[e];
      int pos = offs[d] + atomicAdd(&cursor[d], 1);
      csr[pos] = src[e];
    }
  } else if (bb < 1329) {                // degree scalers
    int idx = (bb - 1250) * 256 + tid;
    if (idx < N_) {
      float d = (float)deg[idx];
      float logd = logf(d + 1.f);
      ampv[idx] = logd / AVG_D_LOG;
      attv[idx] = AVG_D_LOG / fmaxf(logd, 1e-5f);
      invd[idx] = 1.f / fmaxf(d, 1.f);
      hnb[idx] = d > 0.f ? 1.f : 0.f;
    }
  } else {                               // pretrans layer 0 via MFMA
    int n0 = (bb - 1329) * 32;
    int lane = tid & 63, wv = tid >> 6;
    int mt = wv & 1, nh = wv >> 1;
    int l15 = lane & 15, k0q = (lane >> 4) * 8;
    int mrow = n0 + mt * 16 + l15;
    const float* xr = x + (size_t)mrow * 64;
    const _Float16* wb0 = preWT + (size_t)(nh * 64 + l15) * 64 + k0q;
    f4x acc0 = {0.f,0.f,0.f,0.f}, acc1 = {0.f,0.f,0.f,0.f}, acc2 = {0.f,0.f,0.f,0.f}, acc3 = {0.f,0.f,0.f,0.f};
#pragma unroll
    for (int kb = 0; kb < 64; kb += 32) {
      int ko = kb + k0q;
      F4 xa, xb2;
      xa.v = *(const float4*)(xr + ko);
      xb2.v = *(const float4*)(xr + ko + 4);
      h8 af;
      af[0]=(_Float16)xa.f[0]; af[1]=(_Float16)xa.f[1]; af[2]=(_Float16)xa.f[2]; af[3]=(_Float16)xa.f[3];
      af[4]=(_Float16)xb2.f[0]; af[5]=(_Float16)xb2.f[1]; af[6]=(_Float16)xb2.f[2]; af[7]=(_Float16)xb2.f[3];
      acc0 = MFMA16(af, *(const h8*)(wb0 + kb), acc0);
      acc1 = MFMA16(af, *(const h8*)(wb0 + 1024 + kb), acc1);
      acc2 = MFMA16(af, *(const h8*)(wb0 + 2048 + kb), acc2);
      acc3 = MFMA16(af, *(const h8*)(wb0 + 3072 + kb), acc3);
    }
    int rbase = n0 + mt * 16 + (lane >> 4) * 4;
    f4x accs[4] = {acc0, acc1, acc2, acc3};
#pragma unroll
    for (int t = 0; t < 4; t++) {
      int col = nh * 64 + t * 16 + l15;
#pragma unroll
      for (int r = 0; r < 4; r++) {
        int n = rbase + r;
        if (col < 64) ah[(size_t)n * 64 + col] = (_Float16)accs[t][r];
        else          b[(size_t)n * 64 + (col - 64)] = accs[t][r] + preB[col - 64];
      }
    }
  }
}

// ---------------- fused layer (256 threads, 16 nodes, grid 1250) — R16 base ----------------
// R18: phase A ILP 4 -> 8 (eight csr indices + eight gathers in flight),
// halving the dependent-latency rounds at avg degree 16. Everything else
// identical to R16 (the 304 us best).

__global__ __launch_bounds__(256) void k_layer(
    const _Float16* __restrict__ ahin, const float* __restrict__ bin,
    const int* __restrict__ offs, const int* __restrict__ csr,
    const float* __restrict__ invd, const float* __restrict__ hnb,
    const _Float16* __restrict__ WT, const float* __restrict__ Bv,
    const _Float16* __restrict__ mixWT, const float* __restrict__ mixB,
    const float* __restrict__ ampv, const float* __restrict__ attv,
    const float* __restrict__ snorm, float* __restrict__ x,
    const _Float16* __restrict__ preWT, const float* __restrict__ preB,
    _Float16* __restrict__ ahout, float* __restrict__ bout, int do_pre) {
  __shared__ _Float16 aggs[16 * 272];
  __shared__ _Float16 ys[16 * 80];
  __shared__ _Float16 xs[16 * 80];
  int tid = threadIdx.x;
  int n0 = blockIdx.x * 16;
  int lane = tid & 63, wv = tid >> 6;   // wv 0..3

  // ---- phase A: thread = (node nl 0..15, quad q 0..15), ILP8 ----
  {
    int nl = tid >> 4, q = tid & 15;
    int n = n0 + nl;
    int o0 = offs[n];
    int deg = offs[n + 1] - o0;
    float sum[4], sq[4], mx[4], mn[4];
#pragma unroll
    for (int i = 0; i < 4; i++) {
      sum[i] = 0.f; sq[i] = 0.f;
      mx[i] = -__builtin_inff(); mn[i] = __builtin_inff();
    }
    int j = 0;
    for (; j + 7 < deg; j += 8) {
      int s0 = csr[o0 + j];
      int s1 = csr[o0 + j + 1];
      int s2 = csr[o0 + j + 2];
      int s3 = csr[o0 + j + 3];
      int s4 = csr[o0 + j + 4];
      int s5 = csr[o0 + j + 5];
      int s6 = csr[o0 + j + 6];
      int s7 = csr[o0 + j + 7];
      h4 a0 = *(const h4*)(ahin + (size_t)s0 * 64 + q * 4);
      h4 a1 = *(const h4*)(ahin + (size_t)s1 * 64 + q * 4);
      h4 a2 = *(const h4*)(ahin + (size_t)s2 * 64 + q * 4);
      h4 a3 = *(const h4*)(ahin + (size_t)s3 * 64 + q * 4);
      h4 a4 = *(const h4*)(ahin + (size_t)s4 * 64 + q * 4);
      h4 a5 = *(const h4*)(ahin + (size_t)s5 * 64 + q * 4);
      h4 a6 = *(const h4*)(ahin + (size_t)s6 * 64 + q * 4);
      h4 a7 = *(const h4*)(ahin + (size_t)s7 * 64 + q * 4);
#pragma unroll
      for (int i = 0; i < 4; i++) {
        float v0 = (float)a0[i], v1 = (float)a1[i], v2 = (float)a2[i], v3 = (float)a3[i];
        float v4 = (float)a4[i], v5 = (float)a5[i], v6 = (float)a6[i], v7 = (float)a7[i];
        sum[i] += ((v0 + v1) + (v2 + v3)) + ((v4 + v5) + (v6 + v7));
        sq[i] += v0 * v0;
        sq[i] += v1 * v1;
        sq[i] += v2 * v2;
        sq[i] += v3 * v3;
        sq[i] += v4 * v4;
        sq[i] += v5 * v5;
        sq[i] += v6 * v6;
        sq[i] += v7 * v7;
        mx[i] = fmaxf(mx[i], fmaxf(fmaxf(fmaxf(v0, v1), fmaxf(v2, v3)),
                                   fmaxf(fmaxf(v4, v5), fmaxf(v6, v7))));
        mn[i] = fminf(mn[i], fminf(fminf(fminf(v0, v1), fminf(v2, v3)),
                                   fminf(fminf(v4, v5), fminf(v6, v7))));
      }
    }
    for (; j + 3 < deg; j += 4) {
      int s0 = csr[o0 + j];
      int s1 = csr[o0 + j + 1];
      int s2 = csr[o0 + j + 2];
      int s3 = csr[o0 + j + 3];
      h4 a0 = *(const h4*)(ahin + (size_t)s0 * 64 + q * 4);
      h4 a1 = *(const h4*)(ahin + (size_t)s1 * 64 + q * 4);
      h4 a2 = *(const h4*)(ahin + (size_t)s2 * 64 + q * 4);
      h4 a3 = *(const h4*)(ahin + (size_t)s3 * 64 + q * 4);
#pragma unroll
      for (int i = 0; i < 4; i++) {
        float v0 = (float)a0[i], v1 = (float)a1[i], v2 = (float)a2[i], v3 = (float)a3[i];
        sum[i] += (v0 + v1) + (v2 + v3);
        sq[i] += v0 * v0;
        sq[i] += v1 * v1;
        sq[i] += v2 * v2;
        sq[i] += v3 * v3;
        mx[i] = fmaxf(mx[i], fmaxf(fmaxf(v0, v1), fmaxf(v2, v3)));
        mn[i] = fminf(mn[i], fminf(fminf(v0, v1), fminf(v2, v3)));
      }
    }
    for (; j < deg; j++) {
      int s0 = csr[o0 + j];
      h4 a0 = *(const h4*)(ahin + (size_t)s0 * 64 + q * 4);
#pragma unroll
      for (int i = 0; i < 4; i++) {
        float v0 = (float)a0[i];
        sum[i] += v0;
        sq[i] += v0 * v0;
        mx[i] = fmaxf(mx[i], v0);
        mn[i] = fminf(mn[i], v0);
      }
    }
    float inv = invd[n], hn = hnb[n];
    F4 bv; bv.v = *(const float4*)(bin + (size_t)n * 64 + q * 4);
    h4 hm, hx, hmn, hs;
#pragma unroll
    for (int i = 0; i < 4; i++) {
      float mean_a = sum[i] * inv;
      float var = sq[i] * inv - mean_a * mean_a;
      hs[i] = (_Float16)sqrtf(fmaxf(var, 0.f) + 1e-5f);
      bool nb = hn > 0.5f;
      hm[i] = (_Float16)(nb ? (mean_a + bv.f[i]) : 0.f);
      hx[i] = (_Float16)(nb ? (mx[i] + bv.f[i]) : 0.f);
      hmn[i] = (_Float16)(nb ? (mn[i] + bv.f[i]) : 0.f);
    }
    _Float16* ap = aggs + nl * 272 + q * 4;
    *(h4*)(ap) = hm;
    *(h4*)(ap + 64) = hx;
    *(h4*)(ap + 128) = hmn;
    *(h4*)(ap + 192) = hs;
  }
  __syncthreads();

  // ---- phase B: posttrans + mix + graphnorm + residual (one 16-row tile) ----
  int nh = wv;                          // col-quad 0..3
  int l15 = lane & 15, k0q = (lane >> 4) * 8;
  int mrow = n0 + l15;
  const _Float16* ag = aggs + (size_t)l15 * 272 + k0q;
  int col0 = nh * 16 + l15;
  const _Float16* w0 = WT + (size_t)col0 * 832 + k0q;
  f4x aI = {0.f,0.f,0.f,0.f}, aA = {0.f,0.f,0.f,0.f}, aT = {0.f,0.f,0.f,0.f};
#pragma unroll 4
  for (int kb = 0; kb < 256; kb += 32) {
    h8 af = *(const h8*)(ag + kb);
    aI = MFMA16(af, *(const h8*)(w0 + kb), aI);
    aA = MFMA16(af, *(const h8*)(w0 + 256 + kb), aA);
    aT = MFMA16(af, *(const h8*)(w0 + 512 + kb), aT);
  }
  const float* xr = x + (size_t)mrow * 64;
#pragma unroll
  for (int kb = 0; kb < 64; kb += 32) {
    int ko = kb + k0q;
    F4 xa, xb2;
    xa.v = *(const float4*)(xr + ko);
    xb2.v = *(const float4*)(xr + ko + 4);
    h8 af;
    af[0]=(_Float16)xa.f[0]; af[1]=(_Float16)xa.f[1]; af[2]=(_Float16)xa.f[2]; af[3]=(_Float16)xa.f[3];
    af[4]=(_Float16)xb2.f[0]; af[5]=(_Float16)xb2.f[1]; af[6]=(_Float16)xb2.f[2]; af[7]=(_Float16)xb2.f[3];
    aI = MFMA16(af, *(const h8*)(w0 + 768 + kb), aI);
  }
  int qr = (lane >> 4) * 4;
  int rbase = n0 + qr;
  int yrow = qr;
  float b0 = Bv[col0];
#pragma unroll
  for (int r = 0; r < 4; r++) {
    int n = rbase + r;
    float amp = ampv[n], att = attv[n];
    ys[(yrow + r) * 80 + col0] = (_Float16)(aI[r] + b0 + amp * aA[r] + att * aT[r]);
  }
  __syncthreads();
  f4x m0 = {0.f,0.f,0.f,0.f};
  const _Float16* yr = ys + (size_t)l15 * 80 + k0q;
  const _Float16* mw0 = mixWT + (size_t)col0 * 64 + k0q;
#pragma unroll
  for (int kb = 0; kb < 64; kb += 32) {
    h8 af = *(const h8*)(yr + kb);
    m0 = MFMA16(af, *(const h8*)(mw0 + kb), m0);
  }
  float mb0 = mixB[col0];
#pragma unroll
  for (int r = 0; r < 4; r++) {
    int n = rbase + r;
    float sn = snorm[n];
    float t0 = m0[r] + mb0; t0 = t0 > 0.f ? t0 : 0.01f * t0;
    float* xp = x + (size_t)n * 64;
    float xo0 = xp[col0] + t0 * sn;
    xp[col0] = xo0;
    xs[(yrow + r) * 80 + col0] = (_Float16)xo0;
  }

  // ---- phase C: pretrans for layer l+1 from LDS x ----
  if (do_pre) {
    __syncthreads();
    int ch = wv;                       // 32-col chunk 0..3
    const _Float16* xf = xs + (size_t)l15 * 80 + k0q;
    const _Float16* wb0 = preWT + (size_t)(ch * 32 + l15) * 64 + k0q;
    f4x p0 = {0.f,0.f,0.f,0.f}, p1 = {0.f,0.f,0.f,0.f};
#pragma unroll
    for (int kb = 0; kb < 64; kb += 32) {
      h8 af = *(const h8*)(xf + kb);
      p0 = MFMA16(af, *(const h8*)(wb0 + kb), p0);
      p1 = MFMA16(af, *(const h8*)(wb0 + 1024 + kb), p1);
    }
    int prb = n0 + (lane >> 4) * 4;
    f4x accs[2] = {p0, p1};
#pragma unroll
    for (int t = 0; t < 2; t++) {
      int col = ch * 32 + t * 16 + l15;
#pragma unroll
      for (int r = 0; r < 4; r++) {
        int n = prb + r;
        if (col < 64) ahout[(size_t)n * 64 + col] = (_Float16)accs[t][r];
        else          bout[(size_t)n * 64 + (col - 64)] = accs[t][r] + preB[col - 64];
      }
    }
  }
}

// ---------------- fused readout: segmented mean (gid sorted) + MLP ----------------

__device__ inline int lower_bound_gid(const int* __restrict__ gid, int val) {
  int lo = 0, hi = N_;
  while (lo < hi) {
    int mid = (lo + hi) >> 1;
    if (gid[mid] < val) lo = mid + 1; else hi = mid;
  }
  return lo;
}

__global__ __launch_bounds__(256) void k_readout_fused(
    const float* __restrict__ x, const int* __restrict__ gid,
    const float* __restrict__ r1W, const float* __restrict__ r1B,
    const float* __restrict__ r2W, const float* __restrict__ r2B,
    const float* __restrict__ r3W, const float* __restrict__ r3B,
    float* __restrict__ out) {
  __shared__ float part[4 * 64];
  __shared__ float hg[64];
  __shared__ float t1[32];
  __shared__ float t2[16];
  int g = blockIdx.x, tid = threadIdx.x;
  int lo = lower_bound_gid(gid, g);
  int hi = lower_bound_gid(gid, g + 1);
  int c = tid & 63, w = tid >> 6;
  float s = 0.f;
  for (int n = lo + w; n < hi; n += 4) s += x[(size_t)n * 64 + c];
  part[w * 64 + c] = s;
  __syncthreads();
  if (w == 0) {
    float tot = part[c] + part[64 + c] + part[128 + c] + part[192 + c];
    float cnt = (float)(hi - lo);
    if (cnt < 1.f) cnt = 1.f;
    hg[c] = tot / cnt;
  }
  __syncthreads();
  if (tid < 32) {
    float acc = r1B[tid];
#pragma unroll 8
    for (int k = 0; k < 64; k++) acc += hg[k] * r1W[k * 32 + tid];
    t1[tid] = fmaxf(acc, 0.f);
  }
  __syncthreads();
  if (tid < 16) {
    float acc = r2B[tid];
#pragma unroll 8
    for (int k = 0; k < 32; k++) acc += t1[k] * r2W[k * 16 + tid];
    t2[tid] = fmaxf(acc, 0.f);
  }
  __syncthreads();
  if (tid < 10) {
    float acc = r3B[tid];
#pragma unroll
    for (int k = 0; k < 16; k++) acc += t2[k] * r3W[k * 10 + tid];
    out[g * 10 + tid] = acc;
  }
}

// ---------------- launch ----------------

extern "C" void kernel_launch(void* const* d_in, const int* in_sizes, int n_in,
                              void* d_out, int out_size, void* d_ws, size_t ws_size,
                              hipStream_t stream) {
  const float* h     = (const float*)d_in[0];
  const float* snorm = (const float*)d_in[1];
  const float* embW  = (const float*)d_in[2];
  const float* embB  = (const float*)d_in[3];
  const float* preW  = (const float*)d_in[4];
  const float* preB  = (const float*)d_in[5];
  const float* postW = (const float*)d_in[6];
  const float* postB = (const float*)d_in[7];
  const float* mixW  = (const float*)d_in[8];
  const float* mixB  = (const float*)d_in[9];
  const float* r1W   = (const float*)d_in[10];
  const float* r1B   = (const float*)d_in[11];
  const float* r2W   = (const float*)d_in[12];
  const float* r2B   = (const float*)d_in[13];
  const float* r3W   = (const float*)d_in[14];
  const float* r3B   = (const float*)d_in[15];
  const int* src     = (const int*)d_in[16];
  const int* dst     = (const int*)d_in[17];
  const int* gid     = (const int*)d_in[18];
  float* out = (float*)d_out;

  char* w = (char*)d_ws;
  float* x        = (float*)w; w += (size_t)N_ * 64 * 4;
  _Float16* ah0   = (_Float16*)w; w += (size_t)N_ * 64 * 2;
  _Float16* ah1   = (_Float16*)w; w += (size_t)N_ * 64 * 2;
  float* b0       = (float*)w; w += (size_t)N_ * 64 * 4;
  float* b1       = (float*)w; w += (size_t)N_ * 64 * 4;
  _Float16* preWT = (_Float16*)w; w += (size_t)4 * 128 * 64 * 2;
  _Float16* postWT= (_Float16*)w; w += (size_t)4 * 64 * 832 * 2;
  _Float16* mixWT = (_Float16*)w; w += (size_t)4 * 64 * 64 * 2;
  float* ampv = (float*)w; w += (size_t)N_ * 4;
  float* attv = (float*)w; w += (size_t)N_ * 4;
  float* invd = (float*)w; w += (size_t)N_ * 4;
  float* hnb  = (float*)w; w += (size_t)N_ * 4;
  int* csr    = (int*)w;   w += (size_t)E_ * 4;
  int* offs   = (int*)w;   w += (size_t)(N_ + 64) * 4;
  int* zbase  = (int*)w;
  int* deg    = (int*)w;   w += (size_t)N_ * 4;
  int* cursor = (int*)w;   w += (size_t)N_ * 4;

  // 1: embed + weight prep + zero deg/cursor
  k_setup<<<6181, 256, 0, stream>>>(h, embW, embB, x, preW, postW, mixW,
                                    preWT, postWT, mixWT, zbase);
  // 2: degree histogram
  k_hist<<<E_ / 256, 256, 0, stream>>>(dst, deg);
  // 3: offs scan
  k_scan<<<1, 1024, 0, stream>>>(deg, offs);
  // 4: scatter + scalers + pretrans(l0)
  k_mix<<<1250 + 79 + 625, 256, 0, stream>>>(src, dst, offs, cursor, csr, deg,
                                             ampv, attv, invd, hnb,
                                             x, preWT, preB, ah0, b0);
  int gb = N_ / 16;  // 1250 blocks
  _Float16* ahs[2] = {ah0, ah1};
  float* bs[2] = {b0, b1};
  for (int l = 0; l < L_; l++) {
    int pin = l & 1, pout = 1 - pin;
    k_layer<<<gb, 256, 0, stream>>>(ahs[pin], bs[pin], offs, csr, invd, hnb,
                                    postWT + (size_t)l * 53248, postB + l * H_,
                                    mixWT + (size_t)l * 4096, mixB + l * H_,
                                    ampv, attv, snorm, x,
                                    preWT + (size_t)(l + 1 < L_ ? l + 1 : 0) * 8192,
                                    preB + (l + 1 < L_ ? l + 1 : 0) * H_,
                                    ahs[pout], bs[pout], l + 1 < L_ ? 1 : 0);
  }
  k_readout_fused<<<G_, 256, 0, stream>>>(x, gid, r1W, r1B, r2W, r2B, r3W, r3B, out);
}

// Round 19
// 302.481 us; speedup vs baseline: 1.3059x; 1.0815x over previous
//
#include <hip/hip_runtime.h>
#include <math.h>

#define N_ 20000
#define E_ 320000
#define G_ 128
#define IN_ 16
#define H_ 64
#define L_ 4
#define C_ 10
#define AVG_D_LOG 2.8332133440562162f

union F4 { float4 v; float f[4]; };

typedef _Float16 h8 __attribute__((ext_vector_type(8)));
typedef _Float16 h4 __attribute__((ext_vector_type(4)));
typedef float f4x __attribute__((ext_vector_type(4)));
#define MFMA16(a, b, c) __builtin_amdgcn_mfma_f32_16x16x32_f16((a), (b), (c), 0, 0, 0)

// ---------------- fused setup: embed (5000 blk) + weight-prep (1024) + zero (157) ----------------

__global__ __launch_bounds__(256) void k_setup(
    const float* __restrict__ h, const float* __restrict__ embW, const float* __restrict__ embB,
    float* __restrict__ x,
    const float* __restrict__ preW, const float* __restrict__ postW, const float* __restrict__ mixW,
    _Float16* __restrict__ preWT, _Float16* __restrict__ postWT, _Float16* __restrict__ mixWT,
    int* __restrict__ zbase) {
  int bb = blockIdx.x, tid = threadIdx.x;
  if (bb < 5000) {                       // embedding
    int n = bb * 4 + (tid >> 6);
    int c = tid & 63;
    float acc = embB[c];
#pragma unroll
    for (int k = 0; k < IN_; k++) acc += h[n * IN_ + k] * embW[k * H_ + c];
    x[n * H_ + c] = acc;
  } else if (bb < 6024) {                // weight transpose/cast
    int idx = (bb - 5000) * 256 + tid;   // 0 .. 262143
    if (idx < 32768) {                   // preWT [4][128][64]
      int l = idx >> 13, r = idx & 8191;
      int c = r >> 6, k = r & 63;
      preWT[idx] = (_Float16)preW[l * 8192 + k * 64 + c];
    } else if (idx < 245760) {           // postWT [4][64][832]
      int j = idx - 32768;
      int l = j / 53248, r = j % 53248;
      int c = r / 832, k = r % 832;
      postWT[j] = (_Float16)postW[l * 53248 + k * 64 + c];
    } else {                             // mixWT [4][64][64]
      int j = idx - 245760;
      int l = j >> 12, r = j & 4095;
      int c = r >> 6, k = r & 63;
      mixWT[j] = (_Float16)mixW[l * 4096 + k * 64 + c];
    }
  } else {                               // zero deg+cursor
    int i = (bb - 6024) * 256 + tid;
    if (i < 2 * N_) zbase[i] = 0;
  }
}

// ---------------- hist ----------------

__global__ __launch_bounds__(256) void k_hist(const int* __restrict__ dst, int* __restrict__ deg) {
  int e = blockIdx.x * 256 + threadIdx.x;
  if (e < E_) atomicAdd(&deg[dst[e]], 1);
}

// ---------------- scan: offs only ----------------

__global__ __launch_bounds__(1024) void k_scan(const int* __restrict__ deg, int* __restrict__ offs) {
  __shared__ int sh[1024];
  int t = threadIdx.x;
  int base = t * 20;
  int local[20];
  int s = 0;
#pragma unroll
  for (int i = 0; i < 20; i++) {
    int idx = base + i;
    int v = (idx < N_) ? deg[idx] : 0;
    local[i] = s; s += v;
  }
  sh[t] = s;
  __syncthreads();
  for (int off = 1; off < 1024; off <<= 1) {
    int v = (t >= off) ? sh[t - off] : 0;
    __syncthreads();
    sh[t] += v;
    __syncthreads();
  }
  int excl = sh[t] - s;
#pragma unroll
  for (int i = 0; i < 20; i++) {
    int idx = base + i;
    if (idx < N_) offs[idx] = excl + local[i];
  }
  if (t == 0) offs[N_] = sh[1023];
}

// ---------------- fused: scatter (1250) + scalers (79) + pretrans l=0 (625) ----------------

__global__ __launch_bounds__(256) void k_mix(
    const int* __restrict__ src, const int* __restrict__ dst,
    const int* __restrict__ offs, int* __restrict__ cursor, int* __restrict__ csr,
    const int* __restrict__ deg,
    float* __restrict__ ampv, float* __restrict__ attv,
    float* __restrict__ invd, float* __restrict__ hnb,
    const float* __restrict__ x, const _Float16* __restrict__ preWT,
    const float* __restrict__ preB, _Float16* __restrict__ ah, float* __restrict__ b) {
  int bb = blockIdx.x, tid = threadIdx.x;
  if (bb < 1250) {                       // scatter
    int e = bb * 256 + tid;
    if (e < E_) {
      int d = dst[e];
      int pos = offs[d] + atomicAdd(&cursor[d], 1);
      csr[pos] = src[e];
    }
  } else if (bb < 1329) {                // degree scalers
    int idx = (bb - 1250) * 256 + tid;
    if (idx < N_) {
      float d = (float)deg[idx];
      float logd = logf(d + 1.f);
      ampv[idx] = logd / AVG_D_LOG;
      attv[idx] = AVG_D_LOG / fmaxf(logd, 1e-5f);
      invd[idx] = 1.f / fmaxf(d, 1.f);
      hnb[idx] = d > 0.f ? 1.f : 0.f;
    }
  } else {                               // pretrans layer 0 via MFMA
    int n0 = (bb - 1329) * 32;
    int lane = tid & 63, wv = tid >> 6;
    int mt = wv & 1, nh = wv >> 1;
    int l15 = lane & 15, k0q = (lane >> 4) * 8;
    int mrow = n0 + mt * 16 + l15;
    const float* xr = x + (size_t)mrow * 64;
    const _Float16* wb0 = preWT + (size_t)(nh * 64 + l15) * 64 + k0q;
    f4x acc0 = {0.f,0.f,0.f,0.f}, acc1 = {0.f,0.f,0.f,0.f}, acc2 = {0.f,0.f,0.f,0.f}, acc3 = {0.f,0.f,0.f,0.f};
#pragma unroll
    for (int kb = 0; kb < 64; kb += 32) {
      int ko = kb + k0q;
      F4 xa, xb2;
      xa.v = *(const float4*)(xr + ko);
      xb2.v = *(const float4*)(xr + ko + 4);
      h8 af;
      af[0]=(_Float16)xa.f[0]; af[1]=(_Float16)xa.f[1]; af[2]=(_Float16)xa.f[2]; af[3]=(_Float16)xa.f[3];
      af[4]=(_Float16)xb2.f[0]; af[5]=(_Float16)xb2.f[1]; af[6]=(_Float16)xb2.f[2]; af[7]=(_Float16)xb2.f[3];
      acc0 = MFMA16(af, *(const h8*)(wb0 + kb), acc0);
      acc1 = MFMA16(af, *(const h8*)(wb0 + 1024 + kb), acc1);
      acc2 = MFMA16(af, *(const h8*)(wb0 + 2048 + kb), acc2);
      acc3 = MFMA16(af, *(const h8*)(wb0 + 3072 + kb), acc3);
    }
    int rbase = n0 + mt * 16 + (lane >> 4) * 4;
    f4x accs[4] = {acc0, acc1, acc2, acc3};
#pragma unroll
    for (int t = 0; t < 4; t++) {
      int col = nh * 64 + t * 16 + l15;
#pragma unroll
      for (int r = 0; r < 4; r++) {
        int n = rbase + r;
        if (col < 64) ah[(size_t)n * 64 + col] = (_Float16)accs[t][r];
        else          b[(size_t)n * 64 + (col - 64)] = accs[t][r] + preB[col - 64];
      }
    }
  }
}

// ---------------- fused layer (256 threads, 16 nodes, grid 1250) — R16 optimum ----------------
// Measured optimum across: nodes/block {8,16,32} -> 16; phase-A ILP {2,4,8} -> 4;
// threads/block {128,256,512} -> 256. Phase A: thread = (node, quad), ILP4,
// b applied in epilogue. Phase B: 4 waves = 4 col-quads over one 16-row MFMA
// tile. Phase C: 4 waves = 4 col-chunks of 32 for pretrans(l+1).

__global__ __launch_bounds__(256) void k_layer(
    const _Float16* __restrict__ ahin, const float* __restrict__ bin,
    const int* __restrict__ offs, const int* __restrict__ csr,
    const float* __restrict__ invd, const float* __restrict__ hnb,
    const _Float16* __restrict__ WT, const float* __restrict__ Bv,
    const _Float16* __restrict__ mixWT, const float* __restrict__ mixB,
    const float* __restrict__ ampv, const float* __restrict__ attv,
    const float* __restrict__ snorm, float* __restrict__ x,
    const _Float16* __restrict__ preWT, const float* __restrict__ preB,
    _Float16* __restrict__ ahout, float* __restrict__ bout, int do_pre) {
  __shared__ _Float16 aggs[16 * 272];
  __shared__ _Float16 ys[16 * 80];
  __shared__ _Float16 xs[16 * 80];
  int tid = threadIdx.x;
  int n0 = blockIdx.x * 16;
  int lane = tid & 63, wv = tid >> 6;   // wv 0..3

  // ---- phase A: thread = (node nl 0..15, quad q 0..15) ----
  {
    int nl = tid >> 4, q = tid & 15;
    int n = n0 + nl;
    int o0 = offs[n];
    int deg = offs[n + 1] - o0;
    float sum[4], sq[4], mx[4], mn[4];
#pragma unroll
    for (int i = 0; i < 4; i++) {
      sum[i] = 0.f; sq[i] = 0.f;
      mx[i] = -__builtin_inff(); mn[i] = __builtin_inff();
    }
    int j = 0;
    for (; j + 3 < deg; j += 4) {
      int s0 = csr[o0 + j];
      int s1 = csr[o0 + j + 1];
      int s2 = csr[o0 + j + 2];
      int s3 = csr[o0 + j + 3];
      h4 a0 = *(const h4*)(ahin + (size_t)s0 * 64 + q * 4);
      h4 a1 = *(const h4*)(ahin + (size_t)s1 * 64 + q * 4);
      h4 a2 = *(const h4*)(ahin + (size_t)s2 * 64 + q * 4);
      h4 a3 = *(const h4*)(ahin + (size_t)s3 * 64 + q * 4);
#pragma unroll
      for (int i = 0; i < 4; i++) {
        float v0 = (float)a0[i], v1 = (float)a1[i], v2 = (float)a2[i], v3 = (float)a3[i];
        sum[i] += (v0 + v1) + (v2 + v3);
        sq[i] += v0 * v0;
        sq[i] += v1 * v1;
        sq[i] += v2 * v2;
        sq[i] += v3 * v3;
        mx[i] = fmaxf(mx[i], fmaxf(fmaxf(v0, v1), fmaxf(v2, v3)));
        mn[i] = fminf(mn[i], fminf(fminf(v0, v1), fminf(v2, v3)));
      }
    }
    for (; j < deg; j++) {
      int s0 = csr[o0 + j];
      h4 a0 = *(const h4*)(ahin + (size_t)s0 * 64 + q * 4);
#pragma unroll
      for (int i = 0; i < 4; i++) {
        float v0 = (float)a0[i];
        sum[i] += v0;
        sq[i] += v0 * v0;
        mx[i] = fmaxf(mx[i], v0);
        mn[i] = fminf(mn[i], v0);
      }
    }
    float inv = invd[n], hn = hnb[n];
    F4 bv; bv.v = *(const float4*)(bin + (size_t)n * 64 + q * 4);
    h4 hm, hx, hmn, hs;
#pragma unroll
    for (int i = 0; i < 4; i++) {
      float mean_a = sum[i] * inv;
      float var = sq[i] * inv - mean_a * mean_a;
      hs[i] = (_Float16)sqrtf(fmaxf(var, 0.f) + 1e-5f);
      bool nb = hn > 0.5f;
      hm[i] = (_Float16)(nb ? (mean_a + bv.f[i]) : 0.f);
      hx[i] = (_Float16)(nb ? (mx[i] + bv.f[i]) : 0.f);
      hmn[i] = (_Float16)(nb ? (mn[i] + bv.f[i]) : 0.f);
    }
    _Float16* ap = aggs + nl * 272 + q * 4;
    *(h4*)(ap) = hm;
    *(h4*)(ap + 64) = hx;
    *(h4*)(ap + 128) = hmn;
    *(h4*)(ap + 192) = hs;
  }
  __syncthreads();

  // ---- phase B: posttrans + mix + graphnorm + residual (one 16-row tile) ----
  int nh = wv;                          // col-quad 0..3
  int l15 = lane & 15, k0q = (lane >> 4) * 8;
  int mrow = n0 + l15;
  const _Float16* ag = aggs + (size_t)l15 * 272 + k0q;
  int col0 = nh * 16 + l15;
  const _Float16* w0 = WT + (size_t)col0 * 832 + k0q;
  f4x aI = {0.f,0.f,0.f,0.f}, aA = {0.f,0.f,0.f,0.f}, aT = {0.f,0.f,0.f,0.f};
#pragma unroll 4
  for (int kb = 0; kb < 256; kb += 32) {
    h8 af = *(const h8*)(ag + kb);
    aI = MFMA16(af, *(const h8*)(w0 + kb), aI);
    aA = MFMA16(af, *(const h8*)(w0 + 256 + kb), aA);
    aT = MFMA16(af, *(const h8*)(w0 + 512 + kb), aT);
  }
  const float* xr = x + (size_t)mrow * 64;
#pragma unroll
  for (int kb = 0; kb < 64; kb += 32) {
    int ko = kb + k0q;
    F4 xa, xb2;
    xa.v = *(const float4*)(xr + ko);
    xb2.v = *(const float4*)(xr + ko + 4);
    h8 af;
    af[0]=(_Float16)xa.f[0]; af[1]=(_Float16)xa.f[1]; af[2]=(_Float16)xa.f[2]; af[3]=(_Float16)xa.f[3];
    af[4]=(_Float16)xb2.f[0]; af[5]=(_Float16)xb2.f[1]; af[6]=(_Float16)xb2.f[2]; af[7]=(_Float16)xb2.f[3];
    aI = MFMA16(af, *(const h8*)(w0 + 768 + kb), aI);
  }
  int qr = (lane >> 4) * 4;
  int rbase = n0 + qr;
  int yrow = qr;
  float b0 = Bv[col0];
#pragma unroll
  for (int r = 0; r < 4; r++) {
    int n = rbase + r;
    float amp = ampv[n], att = attv[n];
    ys[(yrow + r) * 80 + col0] = (_Float16)(aI[r] + b0 + amp * aA[r] + att * aT[r]);
  }
  __syncthreads();
  f4x m0 = {0.f,0.f,0.f,0.f};
  const _Float16* yr = ys + (size_t)l15 * 80 + k0q;
  const _Float16* mw0 = mixWT + (size_t)col0 * 64 + k0q;
#pragma unroll
  for (int kb = 0; kb < 64; kb += 32) {
    h8 af = *(const h8*)(yr + kb);
    m0 = MFMA16(af, *(const h8*)(mw0 + kb), m0);
  }
  float mb0 = mixB[col0];
#pragma unroll
  for (int r = 0; r < 4; r++) {
    int n = rbase + r;
    float sn = snorm[n];
    float t0 = m0[r] + mb0; t0 = t0 > 0.f ? t0 : 0.01f * t0;
    float* xp = x + (size_t)n * 64;
    float xo0 = xp[col0] + t0 * sn;
    xp[col0] = xo0;
    xs[(yrow + r) * 80 + col0] = (_Float16)xo0;
  }

  // ---- phase C: pretrans for layer l+1 from LDS x ----
  if (do_pre) {
    __syncthreads();
    int ch = wv;                       // 32-col chunk 0..3
    const _Float16* xf = xs + (size_t)l15 * 80 + k0q;
    const _Float16* wb0 = preWT + (size_t)(ch * 32 + l15) * 64 + k0q;
    f4x p0 = {0.f,0.f,0.f,0.f}, p1 = {0.f,0.f,0.f,0.f};
#pragma unroll
    for (int kb = 0; kb < 64; kb += 32) {
      h8 af = *(const h8*)(xf + kb);
      p0 = MFMA16(af, *(const h8*)(wb0 + kb), p0);
      p1 = MFMA16(af, *(const h8*)(wb0 + 1024 + kb), p1);
    }
    int prb = n0 + (lane >> 4) * 4;
    f4x accs[2] = {p0, p1};
#pragma unroll
    for (int t = 0; t < 2; t++) {
      int col = ch * 32 + t * 16 + l15;
#pragma unroll
      for (int r = 0; r < 4; r++) {
        int n = prb + r;
        if (col < 64) ahout[(size_t)n * 64 + col] = (_Float16)accs[t][r];
        else          bout[(size_t)n * 64 + (col - 64)] = accs[t][r] + preB[col - 64];
      }
    }
  }
}

// ---------------- fused readout: segmented mean (gid sorted) + MLP ----------------

__device__ inline int lower_bound_gid(const int* __restrict__ gid, int val) {
  int lo = 0, hi = N_;
  while (lo < hi) {
    int mid = (lo + hi) >> 1;
    if (gid[mid] < val) lo = mid + 1; else hi = mid;
  }
  return lo;
}

__global__ __launch_bounds__(256) void k_readout_fused(
    const float* __restrict__ x, const int* __restrict__ gid,
    const float* __restrict__ r1W, const float* __restrict__ r1B,
    const float* __restrict__ r2W, const float* __restrict__ r2B,
    const float* __restrict__ r3W, const float* __restrict__ r3B,
    float* __restrict__ out) {
  __shared__ float part[4 * 64];
  __shared__ float hg[64];
  __shared__ float t1[32];
  __shared__ float t2[16];
  int g = blockIdx.x, tid = threadIdx.x;
  int lo = lower_bound_gid(gid, g);
  int hi = lower_bound_gid(gid, g + 1);
  int c = tid & 63, w = tid >> 6;
  float s = 0.f;
  for (int n = lo + w; n < hi; n += 4) s += x[(size_t)n * 64 + c];
  part[w * 64 + c] = s;
  __syncthreads();
  if (w == 0) {
    float tot = part[c] + part[64 + c] + part[128 + c] + part[192 + c];
    float cnt = (float)(hi - lo);
    if (cnt < 1.f) cnt = 1.f;
    hg[c] = tot / cnt;
  }
  __syncthreads();
  if (tid < 32) {
    float acc = r1B[tid];
#pragma unroll 8
    for (int k = 0; k < 64; k++) acc += hg[k] * r1W[k * 32 + tid];
    t1[tid] = fmaxf(acc, 0.f);
  }
  __syncthreads();
  if (tid < 16) {
    float acc = r2B[tid];
#pragma unroll 8
    for (int k = 0; k < 32; k++) acc += t1[k] * r2W[k * 16 + tid];
    t2[tid] = fmaxf(acc, 0.f);
  }
  __syncthreads();
  if (tid < 10) {
    float acc = r3B[tid];
#pragma unroll
    for (int k = 0; k < 16; k++) acc += t2[k] * r3W[k * 10 + tid];
    out[g * 10 + tid] = acc;
  }
}

// ---------------- launch ----------------

extern "C" void kernel_launch(void* const* d_in, const int* in_sizes, int n_in,
                              void* d_out, int out_size, void* d_ws, size_t ws_size,
                              hipStream_t stream) {
  const float* h     = (const float*)d_in[0];
  const float* snorm = (const float*)d_in[1];
  const float* embW  = (const float*)d_in[2];
  const float* embB  = (const float*)d_in[3];
  const float* preW  = (const float*)d_in[4];
  const float* preB  = (const float*)d_in[5];
  const float* postW = (const float*)d_in[6];
  const float* postB = (const float*)d_in[7];
  const float* mixW  = (const float*)d_in[8];
  const float* mixB  = (const float*)d_in[9];
  const float* r1W   = (const float*)d_in[10];
  const float* r1B   = (const float*)d_in[11];
  const float* r2W   = (const float*)d_in[12];
  const float* r2B   = (const float*)d_in[13];
  const float* r3W   = (const float*)d_in[14];
  const float* r3B   = (const float*)d_in[15];
  const int* src     = (const int*)d_in[16];
  const int* dst     = (const int*)d_in[17];
  const int* gid     = (const int*)d_in[18];
  float* out = (float*)d_out;

  char* w = (char*)d_ws;
  float* x        = (float*)w; w += (size_t)N_ * 64 * 4;
  _Float16* ah0   = (_Float16*)w; w += (size_t)N_ * 64 * 2;
  _Float16* ah1   = (_Float16*)w; w += (size_t)N_ * 64 * 2;
  float* b0       = (float*)w; w += (size_t)N_ * 64 * 4;
  float* b1       = (float*)w; w += (size_t)N_ * 64 * 4;
  _Float16* preWT = (_Float16*)w; w += (size_t)4 * 128 * 64 * 2;
  _Float16* postWT= (_Float16*)w; w += (size_t)4 * 64 * 832 * 2;
  _Float16* mixWT = (_Float16*)w; w += (size_t)4 * 64 * 64 * 2;
  float* ampv = (float*)w; w += (size_t)N_ * 4;
  float* attv = (float*)w; w += (size_t)N_ * 4;
  float* invd = (float*)w; w += (size_t)N_ * 4;
  float* hnb  = (float*)w; w += (size_t)N_ * 4;
  int* csr    = (int*)w;   w += (size_t)E_ * 4;
  int* offs   = (int*)w;   w += (size_t)(N_ + 64) * 4;
  int* zbase  = (int*)w;
  int* deg    = (int*)w;   w += (size_t)N_ * 4;
  int* cursor = (int*)w;   w += (size_t)N_ * 4;

  // 1: embed + weight prep + zero deg/cursor
  k_setup<<<6181, 256, 0, stream>>>(h, embW, embB, x, preW, postW, mixW,
                                    preWT, postWT, mixWT, zbase);
  // 2: degree histogram
  k_hist<<<E_ / 256, 256, 0, stream>>>(dst, deg);
  // 3: offs scan
  k_scan<<<1, 1024, 0, stream>>>(deg, offs);
  // 4: scatter + scalers + pretrans(l0)
  k_mix<<<1250 + 79 + 625, 256, 0, stream>>>(src, dst, offs, cursor, csr, deg,
                                             ampv, attv, invd, hnb,
                                             x, preWT, preB, ah0, b0);
  int gb = N_ / 16;  // 1250 blocks
  _Float16* ahs[2] = {ah0, ah1};
  float* bs[2] = {b0, b1};
  for (int l = 0; l < L_; l++) {
    int pin = l & 1, pout = 1 - pin;
    k_layer<<<gb, 256, 0, stream>>>(ahs[pin], bs[pin], offs, csr, invd, hnb,
                                    postWT + (size_t)l * 53248, postB + l * H_,
                                    mixWT + (size_t)l * 4096, mixB + l * H_,
                                    ampv, attv, snorm, x,
                                    preWT + (size_t)(l + 1 < L_ ? l + 1 : 0) * 8192,
                                    preB + (l + 1 < L_ ? l + 1 : 0) * H_,
                                    ahs[pout], bs[pout], l + 1 < L_ ? 1 : 0);
  }
  k_readout_fused<<<G_, 256, 0, stream>>>(x, gid, r1W, r1B, r2W, r2B, r3W, r3B, out);
}